// Round 1
// baseline (2770.554 us; speedup 1.0000x reference)
//
#include <hip/hip_runtime.h>
#include <cmath>

#define NB 4
#define NC 128
#define NH 128
#define NW 128
#define HD 64
#define WD 64
#define NL 4096      // 64*64 positions / patches
#define KDIM 1152    // 128*3*3
#define SM_SCALE 2550.0f
#define CUT 40.0f
#define MAXENT 8

struct Ent { int l; float p; };

// Downsample f,b by 2 into fd,bd [NB][NC][64][64]
__global__ void k_prep(const float* __restrict__ f, const float* __restrict__ b,
                       float* __restrict__ fd, float* __restrict__ bd) {
  int i = blockIdx.x * blockDim.x + threadIdx.x;
  if (i >= NB*NC*HD*WD) return;
  int x = i & 63, y = (i >> 6) & 63, c = (i >> 12) & 127, bb = i >> 19;
  int src = ((bb*NC + c)*NH + 2*y)*NW + 2*x;
  fd[i] = f[src];
  bd[i] = b[src];
}

// sq[b][y][x] = sum_c bd^2 (fp64)
__global__ void k_sq(const float* __restrict__ bd, double* __restrict__ sq) {
  int i = blockIdx.x * blockDim.x + threadIdx.x;  // NB*HD*WD
  if (i >= NB*HD*WD) return;
  int x = i & 63, y = (i >> 6) & 63, bb = i >> 12;
  double s = 0.0;
  const float* p = bd + (size_t)bb*NC*HD*WD + y*WD + x;
  for (int c = 0; c < NC; ++c) {
    double v = (double)p[(size_t)c*HD*WD];
    s += v*v;
  }
  sq[i] = s;
}

// norm[b][l] = sqrt(3x3 window sum of sq); mm[b][l] = (mask patch sum == 0)
__global__ void k_normmm(const double* __restrict__ sq, const float* __restrict__ mask,
                         float* __restrict__ norm, float* __restrict__ mmv) {
  int i = blockIdx.x * blockDim.x + threadIdx.x;  // NB*NL
  if (i >= NB*NL) return;
  int pw = i & 63, ph = (i >> 6) & 63, bb = i >> 12;
  double s = 0.0;
  for (int dh = -1; dh <= 1; ++dh) {
    int y = ph + dh; if ((unsigned)y >= 64u) continue;
    for (int dw = -1; dw <= 1; ++dw) {
      int x = pw + dw; if ((unsigned)x >= 64u) continue;
      s += sq[(bb*HD + y)*WD + x];
    }
  }
  norm[i] = (float)sqrt(s);
  float ms = 0.f;
  const float* mb = mask + (size_t)bb*512*512;
  for (int dh = -1; dh <= 1; ++dh) {
    int y = ph + dh; if ((unsigned)y >= 64u) continue;
    for (int dw = -1; dw <= 1; ++dw) {
      int x = pw + dw; if ((unsigned)x >= 64u) continue;
      ms += mb[(y*8)*512 + x*8];
    }
  }
  mmv[i] = (ms == 0.f) ? 1.f : 0.f;
}

// S[p][l] = <f-patch(p), b-patch(l)> / max(norm[l],1e-4). One 64x64 tile per block.
// p-tile = fixed ih (blockIdx.y), all iw; l-tile = fixed ph (blockIdx.x), all pw.
__global__ __launch_bounds__(256) void k_gemm(const float* __restrict__ fd,
    const float* __restrict__ bd, const float* __restrict__ norm,
    float* __restrict__ S, int bb) {
  __shared__ __align__(16) float As[8][64];
  __shared__ __align__(16) float Bs[8][64];
  int tx = threadIdx.x, ty = threadIdx.y;   // 16x16
  int t = ty*16 + tx;
  int ih = blockIdx.y;
  int ph = blockIdx.x;
  const float* fdb = fd + (size_t)bb*NC*HD*WD;
  const float* bdb = bd + (size_t)bb*NC*HD*WD;
  float acc[4][4] = {};
  int kk = t >> 5;          // 0..7 (k within step)
  int j0 = (t & 31) * 2;    // column pair
  for (int k0 = 0; k0 < KDIM; k0 += 8) {
    int k = k0 + kk;
    int c = k / 9, r = k - 9*c;
    int dh = r/3 - 1, dw = r - (r/3)*3 - 1;   // -1..1
    int ya = ih + dh, yb = ph + dh;
    const float* fr = fdb + ((size_t)c*HD + (ya < 0 ? 0 : ya))*WD;
    const float* br = bdb + ((size_t)c*HD + (yb < 0 ? 0 : yb))*WD;
    #pragma unroll
    for (int u = 0; u < 2; ++u) {
      int j = j0 + u;
      int x = j + dw;
      float av = 0.f, bv = 0.f;
      if ((unsigned)x < 64u) {
        if ((unsigned)ya < 64u) av = fdb[((size_t)c*HD + ya)*WD + x];
        if ((unsigned)yb < 64u) bv = bdb[((size_t)c*HD + yb)*WD + x];
      }
      As[kk][j] = av;
      Bs[kk][j] = bv;
    }
    (void)fr; (void)br;
    __syncthreads();
    #pragma unroll
    for (int q = 0; q < 8; ++q) {
      float4 a4 = *(const float4*)&As[q][ty*4];
      float4 b4 = *(const float4*)&Bs[q][tx*4];
      float aa[4] = {a4.x, a4.y, a4.z, a4.w};
      float bv4[4] = {b4.x, b4.y, b4.z, b4.w};
      #pragma unroll
      for (int ii = 0; ii < 4; ++ii)
        #pragma unroll
        for (int jj = 0; jj < 4; ++jj)
          acc[ii][jj] = fmaf(aa[ii], bv4[jj], acc[ii][jj]);
    }
    __syncthreads();
  }
  #pragma unroll
  for (int ii = 0; ii < 4; ++ii) {
    int p = ih*64 + ty*4 + ii;
    #pragma unroll
    for (int jj = 0; jj < 4; ++jj) {
      int l = ph*64 + tx*4 + jj;
      float n = fmaxf(norm[bb*NL + l], 1e-4f);
      S[(size_t)p*NL + l] = acc[ii][jj] / n;
    }
  }
}

// Per score-row: max/argmax, softmax denom, survivor list (sorted by l), offsets.
__global__ __launch_bounds__(256) void k_softmax(const float* __restrict__ S,
    const float* __restrict__ mmv, int* __restrict__ cnt, Ent* __restrict__ ent,
    float* __restrict__ ooff, int bb) {
  int p = blockIdx.x;
  int t = threadIdx.x;
  const float* row = S + (size_t)p*NL;
  const float* mb = mmv + bb*NL;
  float xmax = -3.0e38f;
  float smax = -3.0e38f; int sidx = 0x7fffffff;
  for (int l = t; l < NL; l += 256) {
    float s = row[l];
    float m = mb[l];
    float x = s * SM_SCALE * m;
    xmax = fmaxf(xmax, x);
    if (m != 0.f && s > smax) { smax = s; sidx = l; }   // strict >: first occurrence
  }
  __shared__ float rx[256]; __shared__ float rs[256]; __shared__ int ri[256];
  rx[t] = xmax; rs[t] = smax; ri[t] = sidx;
  __syncthreads();
  for (int o = 128; o > 0; o >>= 1) {
    if (t < o) {
      rx[t] = fmaxf(rx[t], rx[t+o]);
      float s2 = rs[t+o]; int i2 = ri[t+o];
      if (s2 > rs[t] || (s2 == rs[t] && i2 < ri[t])) { rs[t] = s2; ri[t] = i2; }
    }
    __syncthreads();
  }
  xmax = rx[0]; sidx = ri[0];

  __shared__ int count;
  __shared__ int lls[MAXENT];
  __shared__ float les[MAXENT];
  __shared__ float rden[256];
  if (t == 0) count = 0;
  __syncthreads();
  float den = 0.f;
  for (int l = t; l < NL; l += 256) {
    float s = row[l];
    float m = mb[l];
    float x = s * SM_SCALE * m;
    float d = x - xmax;
    if (d > -CUT) {                 // dropped terms < e^-40: negligible vs thr 1.26
      float e = expf(d);
      den += e;
      if (m != 0.f) {
        int slot = atomicAdd(&count, 1);
        if (slot < MAXENT) { lls[slot] = l; les[slot] = e; }
      }
    }
  }
  rden[t] = den;
  __syncthreads();
  for (int o = 128; o > 0; o >>= 1) {
    if (t < o) rden[t] += rden[t+o];
    __syncthreads();
  }
  if (t == 0) {
    float denom = rden[0];
    int n = count; if (n > MAXENT) n = MAXENT;
    // deterministic: insertion-sort survivors by l
    for (int a = 1; a < n; ++a) {
      int lv = lls[a]; float ev = les[a];
      int q = a - 1;
      while (q >= 0 && lls[q] > lv) { lls[q+1] = lls[q]; les[q+1] = les[q]; --q; }
      lls[q+1] = lv; les[q+1] = ev;
    }
    size_t base = (size_t)(bb*NL + p) * MAXENT;
    cnt[bb*NL + p] = n;
    for (int a = 0; a < n; ++a) { ent[base+a].l = lls[a]; ent[base+a].p = les[a]/denom; }
    int off = (sidx == 0x7fffffff) ? 0 : sidx;
    int ihp = p >> 6, iwp = p & 63;
    ooff[((bb*2 + 0)*HD + ihp)*WD + iwp] = (float)((off >> 6) - ihp);
    ooff[((bb*2 + 1)*HD + ihp)*WD + iwp] = (float)((off & 63) - iwp);
  }
}

// y[b,c,oh,ow] = 0.25 * sum over <=4 neighbor positions, their survivors:
//                p_j * b[c, oh+2(ph-ih), ow+2(pw-iw)]  (0 if OOB)
__global__ void k_gather(const float* __restrict__ bsrc, const int* __restrict__ cnt,
                         const Ent* __restrict__ ent, float* __restrict__ yout) {
  int ow = threadIdx.x;       // 128
  int oh = blockIdx.x;        // 128
  int c  = blockIdx.y;        // 128
  int bb = blockIdx.z;        // 4
  const float* bimg = bsrc + ((size_t)bb*NC + c)*NH*NW;
  int ihlo = (oh - 1) >> 1;
  int iwlo = (ow - 1) >> 1;
  float acc = 0.f;
  #pragma unroll
  for (int a = 0; a < 2; ++a) {
    int ih = ihlo + a;
    if ((unsigned)ih >= 64u) continue;
    #pragma unroll
    for (int d = 0; d < 2; ++d) {
      int iw = iwlo + d;
      if ((unsigned)iw >= 64u) continue;
      int pidx = bb*NL + ih*WD + iw;
      int n = cnt[pidx];
      const Ent* ep = ent + (size_t)pidx*MAXENT;
      for (int j = 0; j < n; ++j) {
        Ent e = ep[j];
        int ph = e.l >> 6, pw = e.l & 63;
        int yy = oh + 2*(ph - ih);
        int xx = ow + 2*(pw - iw);
        if ((unsigned)yy < 128u && (unsigned)xx < 128u)
          acc += e.p * bimg[yy*NW + xx];
      }
    }
  }
  yout[(((size_t)bb*NC + c)*NH + oh)*NW + ow] = acc * 0.25f;
}

extern "C" void kernel_launch(void* const* d_in, const int* in_sizes, int n_in,
                              void* d_out, int out_size, void* d_ws, size_t ws_size,
                              hipStream_t stream) {
  const float* f = (const float*)d_in[0];
  const float* b = (const float*)d_in[1];
  const float* mask = (const float*)d_in[2];
  float* out = (float*)d_out;

  char* w = (char*)d_ws;
  float* fd   = (float*)w;  w += (size_t)NB*NC*HD*WD*4;
  float* bd   = (float*)w;  w += (size_t)NB*NC*HD*WD*4;
  double* sq  = (double*)w; w += (size_t)NB*HD*WD*8;
  float* norm = (float*)w;  w += (size_t)NB*NL*4;
  float* mmv  = (float*)w;  w += (size_t)NB*NL*4;
  int* cnt    = (int*)w;    w += (size_t)NB*NL*4;
  Ent* ent    = (Ent*)w;    w += (size_t)NB*NL*MAXENT*sizeof(Ent);
  float* S    = (float*)w;  // 64 MB, reused per batch

  int n1 = NB*NC*HD*WD;
  k_prep<<<(n1+255)/256, 256, 0, stream>>>(f, b, fd, bd);
  k_sq<<<(NB*HD*WD+255)/256, 256, 0, stream>>>(bd, sq);
  k_normmm<<<(NB*NL+255)/256, 256, 0, stream>>>(sq, mask, norm, mmv);

  float* ooff = out + (size_t)NB*NC*NH*NW;
  for (int bb = 0; bb < NB; ++bb) {
    k_gemm<<<dim3(64,64), dim3(16,16), 0, stream>>>(fd, bd, norm, S, bb);
    k_softmax<<<NL, 256, 0, stream>>>(S, mmv, cnt, ent, ooff, bb);
  }
  k_gather<<<dim3(NH, NC, NB), NW, 0, stream>>>(b, cnt, ent, out);
}

// Round 2
// 1141.405 us; speedup vs baseline: 2.4273x; 2.4273x over previous
//
#include <hip/hip_runtime.h>
#include <cmath>

#define NB 4
#define NC 128
#define NH 128
#define NW 128
#define HD 64
#define WD 64
#define NL 4096      // 64*64 positions / patches
#define KDIM 1152    // 128*3*3
#define SM_SCALE 2550.0f
#define CUT 40.0f
#define CUTS 0.216f  // candidate margin in score units: 0.0157 + 2*0.1
#define MAXENT 8
#define MAXC 256

struct Ent { int l; float p; };

typedef __attribute__((ext_vector_type(4))) float f32x4;
typedef __attribute__((ext_vector_type(8))) short s16x8;

__device__ __forceinline__ unsigned short f2bf(float x) {
  unsigned u = __float_as_uint(x);
  return (unsigned short)((u + 0x7fffu + ((u >> 16) & 1u)) >> 16);
}
__device__ __forceinline__ float bf2f(unsigned short h) {
  return __uint_as_float(((unsigned)h) << 16);
}
__device__ __forceinline__ void gload_lds16(const void* g, void* l) {
  __builtin_amdgcn_global_load_lds(
      (const __attribute__((address_space(1))) void*)g,
      (__attribute__((address_space(3))) void*)l, 16, 0, 0);
}

// ---------- prep (unchanged from round 0, exact path) ----------
__global__ void k_prep(const float* __restrict__ f, const float* __restrict__ b,
                       float* __restrict__ fd, float* __restrict__ bd) {
  int i = blockIdx.x * blockDim.x + threadIdx.x;
  if (i >= NB*NC*HD*WD) return;
  int x = i & 63, y = (i >> 6) & 63, c = (i >> 12) & 127, bb = i >> 19;
  int src = ((bb*NC + c)*NH + 2*y)*NW + 2*x;
  fd[i] = f[src];
  bd[i] = b[src];
}

__global__ void k_sq(const float* __restrict__ bd, double* __restrict__ sq) {
  int i = blockIdx.x * blockDim.x + threadIdx.x;
  if (i >= NB*HD*WD) return;
  int x = i & 63, y = (i >> 6) & 63, bb = i >> 12;
  double s = 0.0;
  const float* p = bd + (size_t)bb*NC*HD*WD + y*WD + x;
  for (int c = 0; c < NC; ++c) {
    double v = (double)p[(size_t)c*HD*WD];
    s += v*v;
  }
  sq[i] = s;
}

__global__ void k_normmm(const double* __restrict__ sq, const float* __restrict__ mask,
                         float* __restrict__ norm, float* __restrict__ mmv) {
  int i = blockIdx.x * blockDim.x + threadIdx.x;
  if (i >= NB*NL) return;
  int pw = i & 63, ph = (i >> 6) & 63, bb = i >> 12;
  double s = 0.0;
  for (int dh = -1; dh <= 1; ++dh) {
    int y = ph + dh; if ((unsigned)y >= 64u) continue;
    for (int dw = -1; dw <= 1; ++dw) {
      int x = pw + dw; if ((unsigned)x >= 64u) continue;
      s += sq[(bb*HD + y)*WD + x];
    }
  }
  norm[i] = (float)sqrt(s);
  float ms = 0.f;
  const float* mb = mask + (size_t)bb*512*512;
  for (int dh = -1; dh <= 1; ++dh) {
    int y = ph + dh; if ((unsigned)y >= 64u) continue;
    for (int dw = -1; dw <= 1; ++dw) {
      int x = pw + dw; if ((unsigned)x >= 64u) continue;
      ms += mb[(y*8)*512 + x*8];
    }
  }
  mmv[i] = (ms == 0.f) ? 1.f : 0.f;
}

// ---------- im2col to bf16 (screening path) ----------
__global__ __launch_bounds__(384) void k_im2col(const float* __restrict__ fd,
    const float* __restrict__ bd, unsigned short* __restrict__ Abf,
    unsigned short* __restrict__ Bbf, int bb) {
  int p = blockIdx.x;
  int t = threadIdx.x;
  int ihp = p >> 6, iwp = p & 63;
  const float* fdb = fd + (size_t)bb*NC*HD*WD;
  const float* bdb = bd + (size_t)bb*NC*HD*WD;
  for (int k = t; k < KDIM; k += 384) {
    int c = k / 9, r = k % 9;
    int y = ihp + r/3 - 1, x = iwp + (r % 3) - 1;
    bool inb = ((unsigned)y < 64u) && ((unsigned)x < 64u);
    float av = inb ? fdb[(c*HD + y)*WD + x] : 0.f;
    float bv = inb ? bdb[(c*HD + y)*WD + x] : 0.f;
    Abf[(size_t)p*KDIM + k] = f2bf(av);
    Bbf[(size_t)p*KDIM + k] = f2bf(bv);
  }
}

// ---------- bf16 MFMA screening GEMM: Sb[p][l] = bf16(dot/norm[l]) ----------
// m97 structure: 128x128 tile, BK=32, 4 waves 2x2, 4x4 fragments of 16x16x32.
__global__ __launch_bounds__(256) void k_gemm_bf16(
    const unsigned short* __restrict__ A, const unsigned short* __restrict__ B,
    const float* __restrict__ nrm, unsigned short* __restrict__ Sb) {
  __shared__ __align__(16) unsigned short As[128*32];
  __shared__ __align__(16) unsigned short Bs[128*32];
  int t = threadIdx.x;
  int w = t >> 6, l = t & 63;
  int by = blockIdx.y, bx = blockIdx.x;
  int wr = w >> 1, wc = w & 1;
  f32x4 acc[4][4] = {};
  int aoff[4], boff[4];
  #pragma unroll
  for (int m = 0; m < 4; ++m) {
    aoff[m] = ((wr*64 + m*16 + (l & 15)) * 32 + ((l >> 4) * 8)) * 2;
    boff[m] = ((wc*64 + m*16 + (l & 15)) * 32 + ((l >> 4) * 8)) * 2;
  }
  const char* Ab = (const char*)A;
  const char* Bb = (const char*)B;
  char* AsB = (char*)As;
  char* BsB = (char*)Bs;
  int off = (w*2) * 1024 + l * 16;           // chunk i=0 linear byte offset
  int r0 = off >> 6, cb0 = off & 63;
  int off1 = off + 1024;                      // chunk i=1
  int r1 = off1 >> 6, cb1 = off1 & 63;
  for (int k0 = 0; k0 < KDIM; k0 += 32) {
    gload_lds16(Ab + ((size_t)(by*128 + r0) * KDIM + k0) * 2 + cb0, AsB + (w*2+0)*1024);
    gload_lds16(Ab + ((size_t)(by*128 + r1) * KDIM + k0) * 2 + cb1, AsB + (w*2+1)*1024);
    gload_lds16(Bb + ((size_t)(bx*128 + r0) * KDIM + k0) * 2 + cb0, BsB + (w*2+0)*1024);
    gload_lds16(Bb + ((size_t)(bx*128 + r1) * KDIM + k0) * 2 + cb1, BsB + (w*2+1)*1024);
    __syncthreads();
    s16x8 af[4], bf[4];
    #pragma unroll
    for (int m = 0; m < 4; ++m) af[m] = *(const s16x8*)(AsB + aoff[m]);
    #pragma unroll
    for (int n = 0; n < 4; ++n) bf[n] = *(const s16x8*)(BsB + boff[n]);
    #pragma unroll
    for (int m = 0; m < 4; ++m)
      #pragma unroll
      for (int n = 0; n < 4; ++n)
        acc[m][n] = __builtin_amdgcn_mfma_f32_16x16x32_bf16(af[m], bf[n], acc[m][n], 0, 0, 0);
    __syncthreads();
  }
  int cr = l >> 4;     // 0..3
  int cc = l & 15;
  #pragma unroll
  for (int n = 0; n < 4; ++n) {
    int col = bx*128 + wc*64 + n*16 + cc;
    float rn = 1.f / fmaxf(nrm[col], 1e-4f);
    #pragma unroll
    for (int m = 0; m < 4; ++m) {
      int row0 = by*128 + wr*64 + m*16 + cr*4;
      #pragma unroll
      for (int j = 0; j < 4; ++j) {
        Sb[(size_t)(row0 + j) * NL + col] = f2bf(acc[m][n][j] * rn);
      }
    }
  }
}

// ---------- candidate scan: approx max + collect near-max l's ----------
__global__ __launch_bounds__(256) void k_scan(const unsigned short* __restrict__ Sb,
    const float* __restrict__ mmv, int* __restrict__ ccnt, int* __restrict__ cls,
    int* __restrict__ zcnt, int bb) {
  int p = blockIdx.x, t = threadIdx.x;
  const unsigned short* row = Sb + (size_t)p * NL;
  const float* mb = mmv + bb * NL;
  float s[16]; float m[16];
  int l0 = t * 16;
  uint4 q0 = *(const uint4*)(row + l0);
  uint4 q1 = *(const uint4*)(row + l0 + 8);
  unsigned qq[8] = {q0.x,q0.y,q0.z,q0.w,q1.x,q1.y,q1.z,q1.w};
  #pragma unroll
  for (int j = 0; j < 8; ++j) {
    s[2*j]   = bf2f((unsigned short)(qq[j] & 0xffffu));
    s[2*j+1] = bf2f((unsigned short)(qq[j] >> 16));
  }
  int z = 0; float mx = -3e38f;
  #pragma unroll
  for (int j = 0; j < 16; ++j) {
    m[j] = mb[l0 + j];
    if (m[j] == 0.f) z++;
    else mx = fmaxf(mx, s[j]);
  }
  __shared__ float rmx[256]; __shared__ int rz[256];
  rmx[t] = mx; rz[t] = z;
  __syncthreads();
  for (int o = 128; o > 0; o >>= 1) {
    if (t < o) { rmx[t] = fmaxf(rmx[t], rmx[t+o]); rz[t] += rz[t+o]; }
    __syncthreads();
  }
  float am = rmx[0];
  __shared__ int cnt_s;
  if (t == 0) { cnt_s = 0; zcnt[p] = rz[0]; }
  __syncthreads();
  float thr = am - CUTS;
  #pragma unroll
  for (int j = 0; j < 16; ++j) {
    if (m[j] != 0.f && s[j] >= thr) {
      int slot = atomicAdd(&cnt_s, 1);
      if (slot < MAXC) cls[(size_t)p*MAXC + slot] = l0 + j;
    }
  }
  __syncthreads();
  if (t == 0) ccnt[p] = cnt_s < MAXC ? cnt_s : MAXC;
}

// ---------- exact rescore: fp32 dots (bit-identical chain to round 0), softmax ----------
__global__ __launch_bounds__(256) void k_rescore(const float* __restrict__ fd,
    const float* __restrict__ bd, const float* __restrict__ nrm,
    const int* __restrict__ ccnt, const int* __restrict__ cls,
    const int* __restrict__ zcnt, int* __restrict__ cnt, Ent* __restrict__ ent,
    float* __restrict__ ooff, int bb) {
  int p = blockIdx.x, t = threadIdx.x;
  int ihp = p >> 6, iwp = p & 63;
  __shared__ float fpat[KDIM];
  __shared__ int cl[MAXC];
  __shared__ float cs[MAXC];
  const float* fdb = fd + (size_t)bb*NC*HD*WD;
  const float* bdb = bd + (size_t)bb*NC*HD*WD;
  for (int k = t; k < KDIM; k += 256) {
    int c = k / 9, r = k % 9;
    int y = ihp + r/3 - 1, x = iwp + (r % 3) - 1;
    fpat[k] = (((unsigned)y < 64u) && ((unsigned)x < 64u)) ? fdb[(c*HD + y)*WD + x] : 0.f;
  }
  int nc = ccnt[p];
  for (int a = t; a < nc; a += 256) cl[a] = cls[(size_t)p*MAXC + a];
  __syncthreads();
  if (t == 0 && nc > 1) {        // deterministic order: sort candidates by l
    for (int a = 1; a < nc; ++a) {
      int v = cl[a]; int q = a - 1;
      while (q >= 0 && cl[q] > v) { cl[q+1] = cl[q]; --q; }
      cl[q+1] = v;
    }
  }
  __syncthreads();
  for (int a = t; a < nc; a += 256) {
    int lidx = cl[a]; int ph = lidx >> 6, pw = lidx & 63;
    float acc = 0.f;
    for (int c = 0; c < NC; ++c) {           // k ascending: same fmaf chain as round 0
      const float* bc = bdb + (size_t)c*HD*WD;
      const float* fc = fpat + c*9;
      #pragma unroll
      for (int r = 0; r < 9; ++r) {
        int y = ph + r/3 - 1, x = pw + (r % 3) - 1;
        float bv = (((unsigned)y < 64u) && ((unsigned)x < 64u)) ? bc[y*WD + x] : 0.f;
        acc = fmaf(fc[r], bv, acc);
      }
    }
    cs[a] = acc / fmaxf(nrm[bb*NL + lidx], 1e-4f);
  }
  __syncthreads();
  float smax = -3e38f; int sidx = 0x7fffffff;
  for (int a = t; a < nc; a += 256) {
    if (cs[a] > smax || (cs[a] == smax && cl[a] < sidx)) { smax = cs[a]; sidx = cl[a]; }
  }
  __shared__ float rs[256]; __shared__ int ri[256];
  rs[t] = smax; ri[t] = sidx;
  __syncthreads();
  for (int o = 128; o > 0; o >>= 1) {
    if (t < o) {
      float s2 = rs[t+o]; int i2 = ri[t+o];
      if (s2 > rs[t] || (s2 == rs[t] && i2 < ri[t])) { rs[t] = s2; ri[t] = i2; }
    }
    __syncthreads();
  }
  if (t == 0) {
    smax = rs[0]; sidx = ri[0];
    int Z = zcnt[p];
    size_t base = (size_t)(bb*NL + p) * MAXENT;
    if (nc == 0) {
      cnt[bb*NL + p] = 0;
      ooff[((bb*2 + 0)*HD + ihp)*WD + iwp] = (float)(0 - ihp);
      ooff[((bb*2 + 1)*HD + ihp)*WD + iwp] = (float)(0 - iwp);
    } else {
      float xm = smax * SM_SCALE;
      if (Z > 0) xm = fmaxf(xm, 0.f);
      float den = 0.f;
      for (int a = 0; a < nc; ++a) {
        float d = cs[a] * SM_SCALE - xm;
        if (d > -CUT) den += expf(d);
      }
      if (Z > 0 && -xm > -CUT) den += (float)Z * expf(-xm);
      int n = 0;
      for (int a = 0; a < nc && n < MAXENT; ++a) {
        float d = cs[a] * SM_SCALE - xm;
        if (d > -CUT) { ent[base + n].l = cl[a]; ent[base + n].p = expf(d) / den; ++n; }
      }
      cnt[bb*NL + p] = n;
      ooff[((bb*2 + 0)*HD + ihp)*WD + iwp] = (float)((sidx >> 6) - ihp);
      ooff[((bb*2 + 1)*HD + ihp)*WD + iwp] = (float)((sidx & 63) - iwp);
    }
  }
}

// ---------- gather (unchanged from round 0) ----------
__global__ void k_gather(const float* __restrict__ bsrc, const int* __restrict__ cnt,
                         const Ent* __restrict__ ent, float* __restrict__ yout) {
  int ow = threadIdx.x;
  int oh = blockIdx.x;
  int c  = blockIdx.y;
  int bb = blockIdx.z;
  const float* bimg = bsrc + ((size_t)bb*NC + c)*NH*NW;
  int ihlo = (oh - 1) >> 1;
  int iwlo = (ow - 1) >> 1;
  float acc = 0.f;
  #pragma unroll
  for (int a = 0; a < 2; ++a) {
    int ih = ihlo + a;
    if ((unsigned)ih >= 64u) continue;
    #pragma unroll
    for (int d = 0; d < 2; ++d) {
      int iw = iwlo + d;
      if ((unsigned)iw >= 64u) continue;
      int pidx = bb*NL + ih*WD + iw;
      int n = cnt[pidx];
      const Ent* ep = ent + (size_t)pidx*MAXENT;
      for (int j = 0; j < n; ++j) {
        Ent e = ep[j];
        int ph = e.l >> 6, pw = e.l & 63;
        int yy = oh + 2*(ph - ih);
        int xx = ow + 2*(pw - iw);
        if ((unsigned)yy < 128u && (unsigned)xx < 128u)
          acc += e.p * bimg[yy*NW + xx];
      }
    }
  }
  yout[(((size_t)bb*NC + c)*NH + oh)*NW + ow] = acc * 0.25f;
}

extern "C" void kernel_launch(void* const* d_in, const int* in_sizes, int n_in,
                              void* d_out, int out_size, void* d_ws, size_t ws_size,
                              hipStream_t stream) {
  const float* f = (const float*)d_in[0];
  const float* b = (const float*)d_in[1];
  const float* mask = (const float*)d_in[2];
  float* out = (float*)d_out;

  char* w = (char*)d_ws;
  float* fd   = (float*)w;  w += (size_t)NB*NC*HD*WD*4;
  float* bd   = (float*)w;  w += (size_t)NB*NC*HD*WD*4;
  double* sq  = (double*)w; w += (size_t)NB*HD*WD*8;
  float* norm = (float*)w;  w += (size_t)NB*NL*4;
  float* mmv  = (float*)w;  w += (size_t)NB*NL*4;
  int* cnt    = (int*)w;    w += (size_t)NB*NL*4;
  Ent* ent    = (Ent*)w;    w += (size_t)NB*NL*MAXENT*sizeof(Ent);
  unsigned short* Abf = (unsigned short*)w; w += (size_t)NL*KDIM*2;
  unsigned short* Bbf = (unsigned short*)w; w += (size_t)NL*KDIM*2;
  int* ccnt   = (int*)w;    w += (size_t)NL*4;
  int* zcnt   = (int*)w;    w += (size_t)NL*4;
  int* cls    = (int*)w;    w += (size_t)NL*MAXC*4;
  unsigned short* Sb = (unsigned short*)w;  // 32 MB, reused per batch

  int n1 = NB*NC*HD*WD;
  k_prep<<<(n1+255)/256, 256, 0, stream>>>(f, b, fd, bd);
  k_sq<<<(NB*HD*WD+255)/256, 256, 0, stream>>>(bd, sq);
  k_normmm<<<(NB*NL+255)/256, 256, 0, stream>>>(sq, mask, norm, mmv);

  float* ooff = out + (size_t)NB*NC*NH*NW;
  for (int bb = 0; bb < NB; ++bb) {
    k_im2col<<<NL, 384, 0, stream>>>(fd, bd, Abf, Bbf, bb);
    k_gemm_bf16<<<dim3(32, 32), 256, 0, stream>>>(Abf, Bbf, norm + bb*NL, Sb);
    k_scan<<<NL, 256, 0, stream>>>(Sb, mmv, ccnt, cls, zcnt, bb);
    k_rescore<<<NL, 256, 0, stream>>>(fd, bd, norm, ccnt, cls, zcnt, cnt, ent, ooff, bb);
  }
  k_gather<<<dim3(NH, NC, NB), NW, 0, stream>>>(b, cnt, ent, out);
}

// Round 3
// 769.506 us; speedup vs baseline: 3.6004x; 1.4833x over previous
//
#include <hip/hip_runtime.h>
#include <cmath>

#define NB 4
#define NC 128
#define NH 128
#define NW 128
#define HD 64
#define WD 64
#define NL 4096      // 64*64 positions / patches
#define NPIX 16384   // 128*128 output pixels per batch
#define KDIM 1152    // 128*3*3
#define SM_SCALE 2550.0f
#define CUT 40.0f
#define CUTS 0.216f  // candidate margin in score units
#define MAXENT 8
#define MAXC 256
#define PLMAX 32     // 4 positions x MAXENT survivors
#define CPG 8        // channels per gather thread

struct Ent { int l; float p; };

typedef __attribute__((ext_vector_type(4))) float f32x4;
typedef __attribute__((ext_vector_type(8))) short s16x8;

__device__ __forceinline__ unsigned short f2bf(float x) {
  unsigned u = __float_as_uint(x);
  return (unsigned short)((u + 0x7fffu + ((u >> 16) & 1u)) >> 16);
}
__device__ __forceinline__ float bf2f(unsigned short h) {
  return __uint_as_float(((unsigned)h) << 16);
}
__device__ __forceinline__ unsigned fenc(float v) {   // order-preserving float->uint
  unsigned b = __float_as_uint(v);
  return (b >> 31) ? ~b : (b | 0x80000000u);
}
__device__ __forceinline__ float fdec(unsigned e) {
  unsigned b = (e >> 31) ? (e ^ 0x80000000u) : ~e;    // e==0 -> NaN (no candidates)
  return __uint_as_float(b);
}
__device__ __forceinline__ void gload_lds16(const void* g, void* l) {
  __builtin_amdgcn_global_load_lds(
      (const __attribute__((address_space(1))) void*)g,
      (__attribute__((address_space(3))) void*)l, 16, 0, 0);
}

// ---------- prep ----------
__global__ void k_prep(const float* __restrict__ f, const float* __restrict__ b,
                       float* __restrict__ fd, float* __restrict__ bd) {
  int i = blockIdx.x * blockDim.x + threadIdx.x;
  if (i >= NB*NC*HD*WD) return;
  int x = i & 63, y = (i >> 6) & 63, c = (i >> 12) & 127, bb = i >> 19;
  int src = ((bb*NC + c)*NH + 2*y)*NW + 2*x;
  fd[i] = f[src];
  bd[i] = b[src];
}

__global__ void k_sq(const float* __restrict__ bd, double* __restrict__ sq) {
  int i = blockIdx.x * blockDim.x + threadIdx.x;
  if (i >= NB*HD*WD) return;
  int x = i & 63, y = (i >> 6) & 63, bb = i >> 12;
  double s = 0.0;
  const float* p = bd + (size_t)bb*NC*HD*WD + y*WD + x;
  for (int c = 0; c < NC; ++c) {
    double v = (double)p[(size_t)c*HD*WD];
    s += v*v;
  }
  sq[i] = s;
}

__global__ void k_normmm(const double* __restrict__ sq, const float* __restrict__ mask,
                         float* __restrict__ norm, float* __restrict__ mmv,
                         int* __restrict__ zb) {
  int i = blockIdx.x * blockDim.x + threadIdx.x;
  if (i >= NB*NL) return;
  int pw = i & 63, ph = (i >> 6) & 63, bb = i >> 12;
  double s = 0.0;
  for (int dh = -1; dh <= 1; ++dh) {
    int y = ph + dh; if ((unsigned)y >= 64u) continue;
    for (int dw = -1; dw <= 1; ++dw) {
      int x = pw + dw; if ((unsigned)x >= 64u) continue;
      s += sq[(bb*HD + y)*WD + x];
    }
  }
  norm[i] = (float)sqrt(s);
  float ms = 0.f;
  const float* mb = mask + (size_t)bb*512*512;
  for (int dh = -1; dh <= 1; ++dh) {
    int y = ph + dh; if ((unsigned)y >= 64u) continue;
    for (int dw = -1; dw <= 1; ++dw) {
      int x = pw + dw; if ((unsigned)x >= 64u) continue;
      ms += mb[(y*8)*512 + x*8];
    }
  }
  float m = (ms == 0.f) ? 1.f : 0.f;
  mmv[i] = m;
  if (m == 0.f) atomicAdd(&zb[bb], 1);
}

// ---------- im2col to bf16 ----------
__global__ __launch_bounds__(384) void k_im2col(const float* __restrict__ fd,
    const float* __restrict__ bd, unsigned short* __restrict__ Abf,
    unsigned short* __restrict__ Bbf, int bb) {
  int p = blockIdx.x;
  int t = threadIdx.x;
  int ihp = p >> 6, iwp = p & 63;
  const float* fdb = fd + (size_t)bb*NC*HD*WD;
  const float* bdb = bd + (size_t)bb*NC*HD*WD;
  for (int k = t; k < KDIM; k += 384) {
    int c = k / 9, r = k % 9;
    int y = ihp + r/3 - 1, x = iwp + (r % 3) - 1;
    bool inb = ((unsigned)y < 64u) && ((unsigned)x < 64u);
    float av = inb ? fdb[(c*HD + y)*WD + x] : 0.f;
    float bv = inb ? bdb[(c*HD + y)*WD + x] : 0.f;
    Abf[(size_t)p*KDIM + k] = f2bf(av);
    Bbf[(size_t)p*KDIM + k] = f2bf(bv);
  }
}

// ---------- bf16 MFMA screening GEMM + fused per-row max ----------
__global__ __launch_bounds__(256) void k_gemm_bf16(
    const unsigned short* __restrict__ A, const unsigned short* __restrict__ B,
    const float* __restrict__ nrm, const float* __restrict__ mm,
    unsigned short* __restrict__ Sb, unsigned* __restrict__ rowmax) {
  __shared__ __align__(16) unsigned short As[128*32];
  __shared__ __align__(16) unsigned short Bs[128*32];
  __shared__ unsigned rmx_s[128];
  int t = threadIdx.x;
  int w = t >> 6, l = t & 63;
  int by = blockIdx.y, bx = blockIdx.x;
  int wr = w >> 1, wc = w & 1;
  f32x4 acc[4][4] = {};
  int aoff[4], boff[4];
  #pragma unroll
  for (int m = 0; m < 4; ++m) {
    aoff[m] = ((wr*64 + m*16 + (l & 15)) * 32 + ((l >> 4) * 8)) * 2;
    boff[m] = ((wc*64 + m*16 + (l & 15)) * 32 + ((l >> 4) * 8)) * 2;
  }
  const char* Ab = (const char*)A;
  const char* Bb = (const char*)B;
  char* AsB = (char*)As;
  char* BsB = (char*)Bs;
  int off = (w*2) * 1024 + l * 16;
  int r0 = off >> 6, cb0 = off & 63;
  int off1 = off + 1024;
  int r1 = off1 >> 6, cb1 = off1 & 63;
  for (int k0 = 0; k0 < KDIM; k0 += 32) {
    gload_lds16(Ab + ((size_t)(by*128 + r0) * KDIM + k0) * 2 + cb0, AsB + (w*2+0)*1024);
    gload_lds16(Ab + ((size_t)(by*128 + r1) * KDIM + k0) * 2 + cb1, AsB + (w*2+1)*1024);
    gload_lds16(Bb + ((size_t)(bx*128 + r0) * KDIM + k0) * 2 + cb0, BsB + (w*2+0)*1024);
    gload_lds16(Bb + ((size_t)(bx*128 + r1) * KDIM + k0) * 2 + cb1, BsB + (w*2+1)*1024);
    __syncthreads();
    s16x8 af[4], bf[4];
    #pragma unroll
    for (int m = 0; m < 4; ++m) af[m] = *(const s16x8*)(AsB + aoff[m]);
    #pragma unroll
    for (int n = 0; n < 4; ++n) bf[n] = *(const s16x8*)(BsB + boff[n]);
    #pragma unroll
    for (int m = 0; m < 4; ++m)
      #pragma unroll
      for (int n = 0; n < 4; ++n)
        acc[m][n] = __builtin_amdgcn_mfma_f32_16x16x32_bf16(af[m], bf[n], acc[m][n], 0, 0, 0);
    __syncthreads();
  }
  if (t < 128) rmx_s[t] = 0u;
  __syncthreads();
  int cr = l >> 4;     // 0..3
  int cc = l & 15;
  #pragma unroll
  for (int n = 0; n < 4; ++n) {
    int col = bx*128 + wc*64 + n*16 + cc;
    float rn = 1.f / fmaxf(nrm[col], 1e-4f);
    bool um = (mm[col] != 0.f);
    #pragma unroll
    for (int m = 0; m < 4; ++m) {
      int lrow = wr*64 + m*16 + cr*4;
      int grow = by*128 + lrow;
      #pragma unroll
      for (int j = 0; j < 4; ++j) {
        unsigned short sbv = f2bf(acc[m][n][j] * rn);
        Sb[(size_t)(grow + j) * NL + col] = sbv;
        if (um) atomicMax(&rmx_s[lrow + j], fenc(bf2f(sbv)));
      }
    }
  }
  __syncthreads();
  if (t < 128) atomicMax(&rowmax[by*128 + t], rmx_s[t]);
}

// ---------- candidate scan: one wave per row, single coalesced pass ----------
__global__ __launch_bounds__(256) void k_scan(const unsigned short* __restrict__ Sb,
    const float* __restrict__ mmv, const unsigned* __restrict__ rowmax,
    int* __restrict__ ccnt, int* __restrict__ cls, int bb) {
  int w = threadIdx.x >> 6, lane = threadIdx.x & 63;
  int p = blockIdx.x * 4 + w;
  const unsigned short* row = Sb + (size_t)p * NL;
  const float* mb = mmv + bb * NL;
  float thr = fdec(rowmax[p]) - CUTS;   // NaN if no unmasked col -> no candidates
  __shared__ int cnt_s[4];
  if (lane == 0) cnt_s[w] = 0;
  __syncthreads();
  #pragma unroll
  for (int pass = 0; pass < 8; ++pass) {
    int col = pass*512 + lane*8;
    uint4 q = *(const uint4*)(row + col);
    unsigned qq[4] = {q.x, q.y, q.z, q.w};
    #pragma unroll
    for (int h = 0; h < 4; ++h) {
      float v0 = bf2f((unsigned short)(qq[h] & 0xffffu));
      float v1 = bf2f((unsigned short)(qq[h] >> 16));
      int c0 = col + 2*h, c1 = col + 2*h + 1;
      if (mb[c0] != 0.f && v0 >= thr) {
        int slot = atomicAdd(&cnt_s[w], 1);
        if (slot < MAXC) cls[(size_t)p*MAXC + slot] = c0;
      }
      if (mb[c1] != 0.f && v1 >= thr) {
        int slot = atomicAdd(&cnt_s[w], 1);
        if (slot < MAXC) cls[(size_t)p*MAXC + slot] = c1;
      }
    }
  }
  __syncthreads();
  if (lane == 0) ccnt[p] = cnt_s[w] < MAXC ? cnt_s[w] : MAXC;
}

// ---------- exact rescore: one wave per candidate, lanes over K ----------
__global__ __launch_bounds__(256) void k_rescore(const float* __restrict__ fd,
    const float* __restrict__ bd, const float* __restrict__ nrm,
    const int* __restrict__ ccnt, const int* __restrict__ cls,
    const int* __restrict__ zb, int* __restrict__ cnt, Ent* __restrict__ ent,
    float* __restrict__ ooff, int bb) {
  int p = blockIdx.x, t = threadIdx.x;
  int wid = t >> 6, lane = t & 63;
  int ihp = p >> 6, iwp = p & 63;
  __shared__ float fpat[KDIM];
  __shared__ int cl[MAXC];
  __shared__ float cs[MAXC];
  const float* fdb = fd + (size_t)bb*NC*HD*WD;
  const float* bdb = bd + (size_t)bb*NC*HD*WD;
  for (int k = t; k < KDIM; k += 256) {
    int c = k / 9, r = k % 9;
    int y = ihp + r/3 - 1, x = iwp + (r % 3) - 1;
    fpat[k] = (((unsigned)y < 64u) && ((unsigned)x < 64u)) ? fdb[(c*HD + y)*WD + x] : 0.f;
  }
  int nc = ccnt[p];
  for (int a = t; a < nc; a += 256) cl[a] = cls[(size_t)p*MAXC + a];
  __syncthreads();
  if (t == 0 && nc > 1) {        // deterministic order: sort candidates by l
    for (int a = 1; a < nc; ++a) {
      int v = cl[a]; int q = a - 1;
      while (q >= 0 && cl[q] > v) { cl[q+1] = cl[q]; --q; }
      cl[q+1] = v;
    }
  }
  __syncthreads();
  for (int a = wid; a < nc; a += 4) {
    int lidx = cl[a]; int ph = lidx >> 6, pw = lidx & 63;
    float sum = 0.f;
    #pragma unroll
    for (int kk = 0; kk < 18; ++kk) {     // 1152 = 18*64
      int k = kk*64 + lane;
      int c = k / 9, r = k % 9;
      int y = ph + r/3 - 1, x = pw + (r % 3) - 1;
      float bv = (((unsigned)y < 64u) && ((unsigned)x < 64u)) ? bdb[(c*HD + y)*WD + x] : 0.f;
      sum = fmaf(fpat[k], bv, sum);
    }
    #pragma unroll
    for (int o = 32; o > 0; o >>= 1) sum += __shfl_xor(sum, o, 64);
    if (lane == 0) cs[a] = sum / fmaxf(nrm[bb*NL + lidx], 1e-4f);
  }
  __syncthreads();
  if (t == 0) {
    float smax = -3e38f; int sidx = 0x7fffffff;
    for (int a = 0; a < nc; ++a)
      if (cs[a] > smax) { smax = cs[a]; sidx = cl[a]; }   // sorted by l: first max = smallest l
    int Z = zb[bb];
    size_t base = (size_t)(bb*NL + p) * MAXENT;
    if (nc == 0) {
      cnt[bb*NL + p] = 0;
      ooff[((bb*2 + 0)*HD + ihp)*WD + iwp] = (float)(0 - ihp);
      ooff[((bb*2 + 1)*HD + ihp)*WD + iwp] = (float)(0 - iwp);
    } else {
      float xm = smax * SM_SCALE;
      if (Z > 0) xm = fmaxf(xm, 0.f);
      float den = 0.f;
      for (int a = 0; a < nc; ++a) {
        float d = cs[a] * SM_SCALE - xm;
        if (d > -CUT) den += expf(d);
      }
      if (Z > 0 && -xm > -CUT) den += (float)Z * expf(-xm);
      int n = 0;
      for (int a = 0; a < nc && n < MAXENT; ++a) {
        float d = cs[a] * SM_SCALE - xm;
        if (d > -CUT) { ent[base + n].l = cl[a]; ent[base + n].p = expf(d) / den; ++n; }
      }
      cnt[bb*NL + p] = n;
      ooff[((bb*2 + 0)*HD + ihp)*WD + iwp] = (float)((sidx >> 6) - ihp);
      ooff[((bb*2 + 1)*HD + ihp)*WD + iwp] = (float)((sidx & 63) - iwp);
    }
  }
}

// ---------- plan: per output pixel, channel-independent contribution list ----------
__global__ void k_plan(const int* __restrict__ cnt, const Ent* __restrict__ ent,
                       int* __restrict__ npl, int* __restrict__ offs,
                       float* __restrict__ wts) {
  int i = blockIdx.x * blockDim.x + threadIdx.x;
  if (i >= NB*NPIX) return;
  int pix = i & (NPIX-1); int bb = i >> 14;
  int oh = pix >> 7, ow = pix & 127;
  int ihlo = (oh - 1) >> 1;
  int iwlo = (ow - 1) >> 1;
  int n = 0;
  #pragma unroll
  for (int a = 0; a < 2; ++a) {
    int ih = ihlo + a;
    if ((unsigned)ih >= 64u) continue;
    #pragma unroll
    for (int d = 0; d < 2; ++d) {
      int iw = iwlo + d;
      if ((unsigned)iw >= 64u) continue;
      int pidx = bb*NL + ih*WD + iw;
      int nn = cnt[pidx];
      const Ent* ep = ent + (size_t)pidx*MAXENT;
      for (int j = 0; j < nn; ++j) {
        Ent e = ep[j];
        int ph = e.l >> 6, pw = e.l & 63;
        int yy = oh + 2*(ph - ih);
        int xx = ow + 2*(pw - iw);
        if ((unsigned)yy < 128u && (unsigned)xx < 128u) {
          offs[((size_t)bb*PLMAX + n)*NPIX + pix] = yy*NW + xx;
          wts[((size_t)bb*PLMAX + n)*NPIX + pix] = e.p;
          ++n;
        }
      }
    }
  }
  npl[i] = n;
}

// ---------- gather v2: 8 channels per thread, plan-driven ----------
__global__ __launch_bounds__(128) void k_gather2(const float* __restrict__ bsrc,
    const int* __restrict__ npl, const int* __restrict__ offs,
    const float* __restrict__ wts, float* __restrict__ yout) {
  int ow = threadIdx.x;
  int oh = blockIdx.x;
  int cg = blockIdx.y;
  int bb = blockIdx.z;
  int pix = oh*NW + ow;
  int n = npl[bb*NPIX + pix];
  const float* bimg = bsrc + ((size_t)bb*NC + cg*CPG)*NH*NW;
  float acc[CPG] = {};
  for (int j = 0; j < n; ++j) {
    int off = offs[((size_t)bb*PLMAX + j)*NPIX + pix];
    float wv = wts[((size_t)bb*PLMAX + j)*NPIX + pix];
    #pragma unroll
    for (int c = 0; c < CPG; ++c)
      acc[c] += wv * bimg[c*NH*NW + off];
  }
  float* yp = yout + ((size_t)bb*NC + cg*CPG)*NH*NW + pix;
  #pragma unroll
  for (int c = 0; c < CPG; ++c) yp[c*NH*NW] = acc[c] * 0.25f;
}

extern "C" void kernel_launch(void* const* d_in, const int* in_sizes, int n_in,
                              void* d_out, int out_size, void* d_ws, size_t ws_size,
                              hipStream_t stream) {
  const float* f = (const float*)d_in[0];
  const float* b = (const float*)d_in[1];
  const float* mask = (const float*)d_in[2];
  float* out = (float*)d_out;

  char* w = (char*)d_ws;
  float* fd   = (float*)w;  w += (size_t)NB*NC*HD*WD*4;
  float* bd   = (float*)w;  w += (size_t)NB*NC*HD*WD*4;
  double* sq  = (double*)w; w += (size_t)NB*HD*WD*8;
  float* norm = (float*)w;  w += (size_t)NB*NL*4;
  float* mmv  = (float*)w;  w += (size_t)NB*NL*4;
  int* cnt    = (int*)w;    w += (size_t)NB*NL*4;
  Ent* ent    = (Ent*)w;    w += (size_t)NB*NL*MAXENT*sizeof(Ent);
  unsigned short* Abf = (unsigned short*)w; w += (size_t)NL*KDIM*2;
  unsigned short* Bbf = (unsigned short*)w; w += (size_t)NL*KDIM*2;
  int* ccnt   = (int*)w;    w += (size_t)NL*4;
  int* zb     = (int*)w;    w += 64;
  unsigned* rowmax = (unsigned*)w; w += (size_t)NL*4;
  int* cls    = (int*)w;    w += (size_t)NL*MAXC*4;
  int* npl    = (int*)w;    w += (size_t)NB*NPIX*4;
  int* offs   = (int*)w;    w += (size_t)NB*PLMAX*NPIX*4;
  float* wts  = (float*)w;  w += (size_t)NB*PLMAX*NPIX*4;
  unsigned short* Sb = (unsigned short*)w;  // 32 MB, reused per batch

  int n1 = NB*NC*HD*WD;
  k_prep<<<(n1+255)/256, 256, 0, stream>>>(f, b, fd, bd);
  k_sq<<<(NB*HD*WD+255)/256, 256, 0, stream>>>(bd, sq);
  hipMemsetAsync(zb, 0, 64, stream);
  k_normmm<<<(NB*NL+255)/256, 256, 0, stream>>>(sq, mask, norm, mmv, zb);

  float* ooff = out + (size_t)NB*NC*NH*NW;
  for (int bb = 0; bb < NB; ++bb) {
    hipMemsetAsync(rowmax, 0, (size_t)NL*4, stream);
    k_im2col<<<NL, 384, 0, stream>>>(fd, bd, Abf, Bbf, bb);
    k_gemm_bf16<<<dim3(32, 32), 256, 0, stream>>>(Abf, Bbf, norm + bb*NL, mmv + bb*NL, Sb, rowmax);
    k_scan<<<NL/4, 256, 0, stream>>>(Sb, mmv, rowmax, ccnt, cls, bb);
    k_rescore<<<NL, 256, 0, stream>>>(fd, bd, norm, ccnt, cls, zb, cnt, ent, ooff, bb);
  }
  k_plan<<<(NB*NPIX+255)/256, 256, 0, stream>>>(cnt, ent, npl, offs, wts);
  k_gather2<<<dim3(NH, NC/CPG, NB), 128, 0, stream>>>(b, npl, offs, wts, out);
}